// Round 12
// baseline (369.931 us; speedup 1.0000x reference)
//
#include <hip/hip_runtime.h>
#include <hip/hip_bf16.h>

// Problem constants
#define BATCH 4096
#define IN_SZ 512
#define HID_SZ 2048
#define OUT_SZ 512
#define NLAYER 4
#define INNER 2560        // 512 + 2048
#define NT 80             // K-tiles of 32

// GEMM tile: BM=128 x BN=160, BK=32; grid 32x16 = 512 blocks = 2/CU.
// 256 threads = 4 waves (2M x 2N), per-wave 64x80 (4 m-frags x 5 n-frags).
// TRIPLE-buffered LDS (3 x 20KB = 60KB/block): staging leads use by 2 full
// tiles (~3000 cyc >> 900 cyc HBM miss) so the per-tile vmcnt never stalls.
// 1 barrier + 1 vmcnt(5) + 2 counted lgkm per tile.

typedef __attribute__((ext_vector_type(8))) short bf16x8;
typedef __attribute__((ext_vector_type(4))) float f32x4;

__device__ __forceinline__ unsigned short f2bf(float f) {
  unsigned int u = __float_as_uint(f);
  u += 0x7fff + ((u >> 16) & 1);  // RNE
  return (unsigned short)(u >> 16);
}

__device__ __forceinline__ void gload16(const void* g, void* l) {
  __builtin_amdgcn_global_load_lds(
      (const __attribute__((address_space(1))) unsigned int*)g,
      (__attribute__((address_space(3))) unsigned int*)l,
      16, 0, 0);
}

// ---------------- conversion kernels ----------------

#define NWL4  6553600   // Wl  / 4
#define NWO4  327680    // Wio / 4
#define NWH4  1310720   // Wih / 4
__global__ void cvt_all(const float* __restrict__ Wl, const float* __restrict__ Wih,
                        const float* __restrict__ Wio, unsigned short* __restrict__ dst) {
  const int n4 = NWL4 + NWO4 + NWH4;
  int i = blockIdx.x * blockDim.x + threadIdx.x;
  const int stride = gridDim.x * blockDim.x;
  for (; i < n4; i += stride) {
    const float* src;
    long off4;
    if (i < NWL4) { src = Wl; off4 = i; }
    else if (i < NWL4 + NWO4) { src = Wio; off4 = i - NWL4; }
    else { src = Wih; off4 = i - NWL4 - NWO4; }
    float4 v = *reinterpret_cast<const float4*>(src + off4 * 4);
    ushort4 o;
    o.x = f2bf(v.x); o.y = f2bf(v.y); o.z = f2bf(v.z); o.w = f2bf(v.w);
    *reinterpret_cast<ushort4*>(dst + (long)i * 4) = o;
  }
}

__global__ void build_combined(const float* __restrict__ x,
                               const float* __restrict__ h,
                               unsigned short* __restrict__ out) {
  const int n4 = BATCH * INNER / 4;
  int i = blockIdx.x * blockDim.x + threadIdx.x;
  const int stride = gridDim.x * blockDim.x;
  for (; i < n4; i += stride) {
    int row = i / (INNER / 4);
    int c4 = i - row * (INNER / 4);
    const float* src = (c4 < IN_SZ / 4) ? (x + (long)row * IN_SZ + c4 * 4)
                                        : (h + (long)row * HID_SZ + (c4 - IN_SZ / 4) * 4);
    float4 v = *reinterpret_cast<const float4*>(src);
    ushort4 o;
    o.x = f2bf(v.x); o.y = f2bf(v.y); o.z = f2bf(v.z); o.w = f2bf(v.w);
    *reinterpret_cast<ushort4*>(out + (long)i * 4) = o;
  }
}

// ---------------- 128x160 triple-buffered GEMM: C = act(A*B^T + bias) -------
// A: [4096][2560] bf16, B: [2560][2560] bf16 ('bi,oi->bo').
// LDS buf (20KB): A [0,4096) elems (128 rows x 32), B [4096,9216) (160 x 32),
// pad [9216,10240). Rows are 64B; swizzle: granule ^= (row>>1)&3 (verified:
// each (row,granule) slot hit exactly once per wave -> conflict-free), with
// the inverse pre-applied to the per-lane global source (linear gload_lds dest).
// Staging: 18 real 1KB units (A u0-7, B v0-9) + 2 dead pad units; wave w
// issues units w*5..w*5+4 -> uniform 5 gload16/wave/tile.
// Tile T: stage tile T+2 -> buf (T+2)%3; read frags from buf T%3; lgkm(2)
// (bq+afL) -> 10 MFMA; lgkm(0) -> 10 MFMA; vmcnt(5) (T+1 landed); barrier.
// Overwrite safety: buf (T+2)%3 == buf (T-1)%3, whose reads retired before
// tile T-1's end barrier.

#define SB() __builtin_amdgcn_sched_barrier(0)

#define STAGE(kt, b) do {                                                     \
  _Pragma("unroll")                                                           \
  for (int j_ = 0; j_ < 5; ++j_)                                              \
    gload16(gsrc[j_] + (kt) * 32, (void*)(&lds[b][ldst[j_]]));                \
} while (0)

#define LOAD_BQ(b) do {                                                      \
  _Pragma("unroll")                                                          \
  for (int n_ = 0; n_ < 5; ++n_)                                             \
    bq[n_] = *(const bf16x8*)(&lds[b][0] + bqoff[n_]);                       \
} while (0)

#define LOAD_AFL(b) do {                                                     \
  _Pragma("unroll")                                                          \
  for (int m_ = 0; m_ < 2; ++m_)                                             \
    afL[m_] = *(const bf16x8*)(&lds[b][0] + aoff[m_]);                       \
} while (0)

#define LOAD_AFH(b) do {                                                     \
  _Pragma("unroll")                                                          \
  for (int m_ = 0; m_ < 2; ++m_)                                             \
    afH[m_] = *(const bf16x8*)(&lds[b][0] + aoff[2 + m_]);                   \
} while (0)

#define MF_HALF(af, mh) do {                                                  \
  __builtin_amdgcn_s_setprio(1);                                              \
  _Pragma("unroll")                                                           \
  for (int m_ = 0; m_ < 2; ++m_)                                              \
    _Pragma("unroll")                                                         \
    for (int n_ = 0; n_ < 5; ++n_)                                            \
      acc[(mh) * 2 + m_][n_] = __builtin_amdgcn_mfma_f32_16x16x32_bf16(       \
          af[m_], bq[n_], acc[(mh) * 2 + m_][n_], 0, 0, 0);                   \
  __builtin_amdgcn_s_setprio(0);                                              \
} while (0)

#define TILE(BT, BS, ktv) do {                                                \
  STAGE(ktv, BS);                                                             \
  LOAD_BQ(BT);                                                                \
  LOAD_AFL(BT);                                                               \
  LOAD_AFH(BT);                                                               \
  SB();                                                                       \
  asm volatile("s_waitcnt lgkmcnt(2)" ::: "memory");  /* bq+afL ready */      \
  SB();                                                                       \
  MF_HALF(afL, 0);                                                            \
  asm volatile("s_waitcnt lgkmcnt(0)" ::: "memory");  /* afH ready */         \
  SB();                                                                       \
  MF_HALF(afH, 1);                                                            \
  asm volatile("s_waitcnt vmcnt(5)" ::: "memory");  /* tile T+1 landed */     \
  __builtin_amdgcn_s_barrier();                                               \
} while (0)

template <int MODE>
__global__ __launch_bounds__(256, 2)
void gemm_tb(const unsigned short* __restrict__ A, const unsigned short* __restrict__ B,
             const float* __restrict__ bias0, const float* __restrict__ bias1,
             void* __restrict__ C) {
  __shared__ unsigned short lds[3][10240];  // 60 KiB

  const int tid = threadIdx.x;
  const int w = tid >> 6;   // 4 waves
  const int lane = tid & 63;

  // XCD mapping: 512 blocks; each XCD owns 2 adjacent 160-col B panels
  const int flat = blockIdx.x;
  const int xcd = flat & 7;
  const int local = flat >> 3;           // 0..63
  const int nb = xcd * 2 + (local & 1);  // 16 N-blocks
  const int mb = local >> 1;             // 32 M-blocks
  const int row0 = mb * 128, col0 = nb * 160;
  const int wr = w >> 1, wcn = w & 1;
  const int fr = lane & 15;
  const int g4 = lane >> 4;

  // staging sources (5 units/wave) + LDS element dests (within a buf)
  const unsigned short* gsrc[5];
  int ldst[5];
  {
    const int srow = lane >> 2;                                 // row in unit
    const int scol = (((lane & 3) ^ ((lane >> 3) & 3)) * 8);    // swz source col
#pragma unroll
    for (int j = 0; j < 5; ++j) {
      const int ui = w * 5 + j;
      if (ui < 8) {         // A unit: rows ui*16..+15
        gsrc[j] = A + (long)(row0 + ui * 16 + srow) * INNER + scol;
        ldst[j] = ui * 512;
      } else if (ui < 18) { // B unit
        const int vi = ui - 8;
        gsrc[j] = B + (long)(col0 + vi * 16 + srow) * INNER + scol;
        ldst[j] = 4096 + vi * 512;
      } else {              // dead pad unit (wave 3 only)
        gsrc[j] = A + (long)(row0 + srow) * INNER + scol;
        ldst[j] = 9216 + (ui - 18) * 512;
      }
    }
  }

  // fragment read offsets (elements), fixed per thread
  int bqoff[5], aoff[4];
#pragma unroll
  for (int n = 0; n < 5; ++n) {
    const int r = wcn * 80 + n * 16 + fr;
    bqoff[n] = 4096 + r * 32 + ((g4 ^ ((r >> 1) & 3)) << 3);
  }
#pragma unroll
  for (int m = 0; m < 4; ++m) {
    const int r = wr * 64 + m * 16 + fr;
    aoff[m] = r * 32 + ((g4 ^ ((r >> 1) & 3)) << 3);
  }

  f32x4 acc[4][5] = {};
  bf16x8 bq[5], afL[2], afH[2];

  // prologue: tiles 0 -> buf0, 1 -> buf1
  STAGE(0, 0);
  STAGE(1, 1);
  asm volatile("s_waitcnt vmcnt(5)" ::: "memory");  // tile 0 landed
  __builtin_amdgcn_s_barrier();
  SB();

  for (int T = 0; T < 78; T += 3) {
    TILE(0, 2, T + 2);
    TILE(1, 0, T + 3);
    TILE(2, 1, T + 4);
  }
  TILE(0, 2, 79);  // tile 78; dup-stage 79 (never read from buf2)
  TILE(1, 0, 79);  // tile 79; dup-stage 79 (never read from buf0)
  asm volatile("s_waitcnt vmcnt(0)" ::: "memory");

  // epilogue: C/D layout col = lane&15, row = (lane>>4)*4 + j
  const int erow = row0 + wr * 64 + (g4 << 2);
  const int ecol = col0 + wcn * 80 + fr;
  if (MODE == 0) {
    unsigned short* Co = (unsigned short*)C;
#pragma unroll
    for (int n = 0; n < 5; ++n) {
      const int col = ecol + n * 16;
      const float bv = bias0[col];
#pragma unroll
      for (int m = 0; m < 4; ++m) {
        const int row = erow + m * 16;
#pragma unroll
        for (int j = 0; j < 4; ++j) {
          float v = acc[m][n][j] + bv;
          v = fmaxf(v, 0.0f);
          Co[(long)(row + j) * INNER + col] = f2bf(v);
        }
      }
    }
  } else {
    float* outO = (float*)C;                          // [4096,512]
    float* outH = (float*)C + (long)BATCH * OUT_SZ;   // [4096,2048]
#pragma unroll
    for (int n = 0; n < 5; ++n) {
      const int col = ecol + n * 16;
      if (col < OUT_SZ) {
        const float bv = bias0[col];
#pragma unroll
        for (int m = 0; m < 4; ++m) {
          const int row = erow + m * 16;
#pragma unroll
          for (int j = 0; j < 4; ++j)
            outO[(long)(row + j) * OUT_SZ + col] = acc[m][n][j] + bv;
        }
      } else {
        const int hc = col - OUT_SZ;
        const float bv = bias1[hc];
#pragma unroll
        for (int m = 0; m < 4; ++m) {
          const int row = erow + m * 16;
#pragma unroll
          for (int j = 0; j < 4; ++j)
            outH[(long)(row + j) * HID_SZ + hc] = tanhf(acc[m][n][j] + bv);
        }
      }
    }
  }
}

// ---------------- launcher ----------------

extern "C" void kernel_launch(void* const* d_in, const int* in_sizes, int n_in,
                              void* d_out, int out_size, void* d_ws, size_t ws_size,
                              hipStream_t stream) {
  const float* x   = (const float*)d_in[0];
  const float* h   = (const float*)d_in[1];
  const float* Wl  = (const float*)d_in[2];  // [4,2560,2560]
  const float* bl  = (const float*)d_in[3];  // [4,2560]
  const float* Wih = (const float*)d_in[4];  // [2048,2560]
  const float* bih = (const float*)d_in[5];  // [2048]
  const float* Wio = (const float*)d_in[6];  // [512,2560]
  const float* bio = (const float*)d_in[7];  // [512]

  unsigned short* ws   = (unsigned short*)d_ws;
  unsigned short* Wlb  = ws;                                   // 4*2560*2560
  unsigned short* Whb  = Wlb + (long)NLAYER * INNER * INNER;   // fused heads [2560][2560]
  unsigned short* act0 = Whb + (long)INNER * INNER;
  unsigned short* act1 = act0 + (long)BATCH * INNER;

  // fp32 -> bf16 weight conversion (dst contiguous: Wl ++ Wio ++ Wih)
  cvt_all<<<2048, 256, 0, stream>>>(Wl, Wih, Wio, Wlb);
  build_combined<<<2048, 256, 0, stream>>>(x, h, act0);

  // 4 square layers, ping-pong
  unsigned short* a_in = act0;
  unsigned short* a_out = act1;
  for (int l = 0; l < NLAYER; ++l) {
    gemm_tb<0><<<512, 256, 0, stream>>>(a_in, Wlb + (long)l * INNER * INNER,
                                        bl + (long)l * INNER, nullptr, a_out);
    unsigned short* t = a_in; a_in = a_out; a_out = t;
  }

  // fused heads: output (cols 0-511) + tanh hidden (cols 512-2559)
  gemm_tb<1><<<512, 256, 0, stream>>>(a_in, Whb, bio, bih, d_out);
}